// Round 3
// baseline (489.571 us; speedup 1.0000x reference)
//
#include <hip/hip_runtime.h>
#include <hip/hip_cooperative_groups.h>

namespace cg = cooperative_groups;

// Problem constants (fixed by the reference file)
#define N_ELEM   4194304
#define NUM_IDS  262144
#define M_CAP    (NUM_IDS + 1)       // 262145
#define L_CAP    128

#define NBLK 1024
#define NTHR 256
#define TOTAL_THREADS (NBLK * NTHR)  // 262144
#define EPT 16                        // elements per thread = N_ELEM / TOTAL_THREADS

#define P_TOTAL   (M_CAP * L_CAP)     // 33554560 padded elements
#define OUT_TOTAL (M_CAP + P_TOTAL)   // 33816705 floats in d_out
#define Q0        (M_CAP + 3)         // 262148: first 16B-aligned float index in padded region
#define NF4       ((OUT_TOTAL - Q0) / 4)  // 8388639 float4 stores; 1 leftover float at the end

// ---------------------------------------------------------------------------
// Single cooperative kernel.
// Phase 1: each thread loads 16 consecutive ids (kept in VGPRs), flags run
//          starts, block-scans the start counts -> partial[block].
// Phase 2: block 0 scans the 1024 partials -> offsets[], num_runs.
// Phase 3: each thread re-walks its registers and scatters
//          run_start[rank] = elem index, run_vid[rank] = id.
//          (runs are contiguous: end[m] == run_start[m+1] -- no end array)
// Phase 4: output. run_ids region: 1 float/thread. Padded region: flat
//          float4 stores at q = Q0 + 4k (always 16B aligned); per element
//          m = p>>7, col = p&127; feat loads exec-predicated on col < len.
// ---------------------------------------------------------------------------
__global__ void __launch_bounds__(NTHR, 1)
k_fused(const int* __restrict__ ids,
        const float* __restrict__ feat,
        float* __restrict__ out,
        int* __restrict__ ws) {
    // Workspace layout (ints)
    int* partial    = ws;                    // NBLK
    int* offsets    = ws + NBLK;             // NBLK
    int* num_runs_p = ws + 2 * NBLK;         // 1 (padded to 4)
    int* run_start  = ws + 2 * NBLK + 4;     // M_CAP (padded to 262148)
    int* run_vid    = run_start + 262148;    // M_CAP

    const int b = blockIdx.x, t = threadIdx.x;
    const int gtid = b * NTHR + t;
    cg::grid_group grid = cg::this_grid();
    __shared__ int sm[NTHR];

    // ---- Phase 1: boundary flags + block scan of start counts ----
    const int base = gtid * EPT;
    int v[EPT];
    {
        const int4* p4 = (const int4*)(ids + base);
        int4 a = p4[0], b4 = p4[1], c4 = p4[2], d4 = p4[3];
        v[0]=a.x; v[1]=a.y; v[2]=a.z; v[3]=a.w;
        v[4]=b4.x; v[5]=b4.y; v[6]=b4.z; v[7]=b4.w;
        v[8]=c4.x; v[9]=c4.y; v[10]=c4.z; v[11]=c4.w;
        v[12]=d4.x; v[13]=d4.y; v[14]=d4.z; v[15]=d4.w;
    }
    const int prev = (gtid == 0) ? -1 : ids[base - 1];  // ids >= 0, so -1 => start

    int c = 0;
    int flag[EPT];
#pragma unroll
    for (int j = 0; j < EPT; ++j) {
        flag[j] = (v[j] != ((j == 0) ? prev : v[j - 1]));
        c += flag[j];
    }

    sm[t] = c;
    __syncthreads();
    for (int off = 1; off < NTHR; off <<= 1) {
        int val = (t >= off) ? sm[t - off] : 0;
        __syncthreads();
        if (t >= off) sm[t] += val;
        __syncthreads();
    }
    const int texcl = sm[t] - c;            // exclusive prefix within block
    if (t == NTHR - 1) partial[b] = sm[NTHR - 1];

    grid.sync();

    // ---- Phase 2: block 0 scans the 1024 block partials ----
    if (b == 0) {
        int4 pp = ((const int4*)partial)[t];
        int s1 = pp.x + pp.y, s2 = s1 + pp.z, tsum = s2 + pp.w;
        sm[t] = tsum;
        __syncthreads();
        for (int off = 1; off < NTHR; off <<= 1) {
            int val = (t >= off) ? sm[t - off] : 0;
            __syncthreads();
            if (t >= off) sm[t] += val;
            __syncthreads();
        }
        int excl = sm[t] - tsum;
        int4 r;
        r.x = excl; r.y = excl + pp.x; r.z = excl + s1; r.w = excl + s2;
        ((int4*)offsets)[t] = r;
        if (t == NTHR - 1) num_runs_p[0] = sm[NTHR - 1];
    }

    grid.sync();

    // ---- Phase 3: scatter run_start / run_vid by rank (from registers) ----
    {
        int rank = offsets[b] + texcl;
#pragma unroll
        for (int j = 0; j < EPT; ++j) {
            if (flag[j]) {
                run_start[rank] = base + j;
                run_vid[rank]   = v[j];
                ++rank;
            }
        }
    }

    grid.sync();

    // ---- Phase 4: write output ----
    const int num_valid = num_runs_p[0] - 1;

    // run_ids region: out[0 .. NUM_IDS) one float per thread
    {
        int rv = run_vid[gtid];   // in-bounds; poison masked by the select
        out[gtid] = (gtid < num_valid) ? (float)rv : -1.0f;
    }

    if (gtid == 0) {
        // last run_id slot (num_valid <= NUM_IDS-1 always)
        out[M_CAP - 1] = -1.0f;
        // padded elements p = 0,1,2 (before the aligned f4 region)
        int s0 = 0, len0 = 0;
        if (num_valid > 0) {
            s0 = run_start[0];
            int e0 = run_start[1];
            len0 = min(e0 - s0, L_CAP);
        }
#pragma unroll
        for (int p = 0; p < 3; ++p)
            out[M_CAP + p] = (p < len0) ? feat[s0 + p] : 0.0f;
        // final leftover float: p = P_TOTAL-1 -> m = M_CAP-1 >= num_valid -> 0
        out[OUT_TOTAL - 1] = 0.0f;
    }

    // padded region: float4 per iteration, 16B aligned
    for (int k = gtid; k < NF4; k += TOTAL_THREADS) {
        const int p  = 3 + 4 * k;          // padded-region element index
        const int m0 = p >> 7;
        const int m3 = (p + 3) >> 7;       // == m0 except when (p&127) == 127 wraps

        int s0 = 0, len0 = 0;
        if (m0 < num_valid) {
            s0 = run_start[m0];
            len0 = min(run_start[m0 + 1] - s0, L_CAP);
        }
        int s3 = s0, len3 = len0;
        if (m3 != m0) {
            s3 = 0; len3 = 0;
            if (m3 < num_valid) {
                s3 = run_start[m3];
                len3 = min(run_start[m3 + 1] - s3, L_CAP);
            }
        }

        float4 r;
        {
            int pj, cj, s, L;
            pj = p;     cj = pj & 127; s = (pj>>7)==m0 ? s0 : s3; L = (pj>>7)==m0 ? len0 : len3;
            r.x = (cj < L) ? feat[s + cj] : 0.0f;
            pj = p + 1; cj = pj & 127; s = (pj>>7)==m0 ? s0 : s3; L = (pj>>7)==m0 ? len0 : len3;
            r.y = (cj < L) ? feat[s + cj] : 0.0f;
            pj = p + 2; cj = pj & 127; s = (pj>>7)==m0 ? s0 : s3; L = (pj>>7)==m0 ? len0 : len3;
            r.z = (cj < L) ? feat[s + cj] : 0.0f;
            pj = p + 3; cj = pj & 127; s = (pj>>7)==m0 ? s0 : s3; L = (pj>>7)==m0 ? len0 : len3;
            r.w = (cj < L) ? feat[s + cj] : 0.0f;
        }
        *(float4*)(out + Q0 + 4 * (size_t)k) = r;
    }
}

// ---------------------------------------------------------------------------
extern "C" void kernel_launch(void* const* d_in, const int* in_sizes, int n_in,
                              void* d_out, int out_size, void* d_ws, size_t ws_size,
                              hipStream_t stream) {
    const int* ids = (const int*)d_in[0];      // int32
    const float* feat = (const float*)d_in[1]; // float32
    float* out = (float*)d_out;                // float32
    int* ws = (int*)d_ws;

    void* args[] = { (void*)&ids, (void*)&feat, (void*)&out, (void*)&ws };
    hipLaunchCooperativeKernel((void*)k_fused, dim3(NBLK), dim3(NTHR),
                               args, 0, stream);
}

// Round 4
// 323.749 us; speedup vs baseline: 1.5122x; 1.5122x over previous
//
#include <hip/hip_runtime.h>

// Problem constants (fixed by the reference file)
#define N_ELEM   4194304
#define NUM_IDS  262144
#define M_CAP    (NUM_IDS + 1)       // 262145
#define L_CAP    128

#define NTILES   1024
#define TILE     4096                // NTILES * TILE == N_ELEM
#define NTHR     256
#define EPT      16                  // TILE / NTHR, contiguous per thread

// ws layout (uint words):
//  [0]              ticket counter
//  [1]              total word: 0 until set, then (1<<30)|num_runs
//  [2..3]           pad
//  [4 .. 4+NTILES)  tile words: 0=invalid, (1<<30)|aggregate, (2<<30)|incl_prefix
#define WS_TICKET 0
#define WS_TOTAL  1
#define WS_TILES  4
#define WS_WORDS  (WS_TILES + NTILES)

#define ST_SHIFT  30
#define ST_AGG    (1u << ST_SHIFT)
#define ST_PRE    (2u << ST_SHIFT)
#define VAL_MASK  ((1u << ST_SHIFT) - 1u)

// ---------------------------------------------------------------------------
// Single-pass: per-tile run detection + decoupled-lookback scan of run counts
// + fused emission (each block writes the output rows of the runs it found).
// Runs are contiguous: end[r] == start[r+1]; only the block's last run needs
// a <=128-element peek past the tile boundary (len is capped at L_CAP anyway).
// The globally-final run is never emitted (reference semantics); the
// last-ticket block knows num_runs and fills rows [num_runs-1, M_CAP) with
// -1 / zeros. Row ownership is disjoint -> no inter-block write races.
// ---------------------------------------------------------------------------
__global__ void __launch_bounds__(NTHR)
k_scan_emit(const int* __restrict__ ids,
            const float* __restrict__ feat,
            float* __restrict__ out,
            unsigned int* __restrict__ ws) {
    __shared__ int sm[NTHR];
    __shared__ int lds_start[TILE + 1];
    __shared__ int lds_bc[3];   // 0: vtile, 1: prefix, 2: num_runs

    const int t = threadIdx.x;

    // ---- ticket: virtual tile id (deadlock-free ordering) ----
    if (t == 0) lds_bc[0] = (int)atomicAdd(&ws[WS_TICKET], 1u);
    __syncthreads();
    const int vt = lds_bc[0];
    const int tile_base = vt * TILE;
    const int tile_end  = tile_base + TILE;   // == N_ELEM for the last tile

    // ---- phase 1: run-start flags for 16 contiguous ids per thread ----
    const int base = tile_base + t * EPT;
    unsigned int flagbits = 0;
    int c = 0;
    {
        int prev = (base == 0) ? -1 : ids[base - 1];   // ids >= 0 -> sentinel
        const int4* p4 = (const int4*)(ids + base);
#pragma unroll
        for (int g = 0; g < 4; ++g) {
            int4 q = p4[g];
            unsigned f0 = (q.x != prev);
            unsigned f1 = (q.y != q.x);
            unsigned f2 = (q.z != q.y);
            unsigned f3 = (q.w != q.z);
            flagbits |= (f0 << (4*g)) | (f1 << (4*g+1)) | (f2 << (4*g+2)) | (f3 << (4*g+3));
            c += (int)(f0 + f1 + f2 + f3);
            prev = q.w;
        }
    }

    // ---- block scan of per-thread start counts ----
    sm[t] = c;
    __syncthreads();
    for (int off = 1; off < NTHR; off <<= 1) {
        int val = (t >= off) ? sm[t - off] : 0;
        __syncthreads();
        if (t >= off) sm[t] += val;
        __syncthreads();
    }
    const int excl = sm[t] - c;        // exclusive prefix within block
    const int cnt  = sm[NTHR - 1];     // tile's run-start count

    // ---- publish aggregate ASAP (unblocks successors' lookback) ----
    if (t == 0) {
        unsigned w = (vt == 0) ? (ST_PRE | (unsigned)cnt) : (ST_AGG | (unsigned)cnt);
        __hip_atomic_store(&ws[WS_TILES + vt], w, __ATOMIC_RELEASE, __HIP_MEMORY_SCOPE_AGENT);
    }

    // ---- scatter local run starts into LDS (element order == thread order) ----
    {
        int r = excl;
#pragma unroll
        for (int j = 0; j < EPT; ++j)
            if (flagbits & (1u << j)) { lds_start[r] = base + j; ++r; }
    }
    __syncthreads();

    // ---- wave 0: resolve end of the tile's last run -> lds_start[cnt] ----
    if (t < 64) {
        if (cnt > 0) {
            int s_last = lds_start[cnt - 1];
            int e = tile_end;   // last in-tile start's run reaches at least tile_end
            if (tile_end < N_ELEM && (tile_end - s_last) < L_CAP) {
                int vid = ids[s_last];
                int idx0 = tile_end + t;
                int m0 = (idx0 < N_ELEM) ? (ids[idx0] != vid) : 1;
                int idx1 = idx0 + 64;
                int m1 = (idx1 < N_ELEM) ? (ids[idx1] != vid) : 1;
                unsigned long long b0 = __ballot(m0);
                unsigned long long b1 = __ballot(m1);
                int ext;
                if (b0)      ext = __ffsll(b0) - 1;
                else if (b1) ext = 64 + __ffsll(b1) - 1;
                else         ext = 2 * 64;          // >=128 past tile_end -> cap hits
                e = tile_end + ext;
            }
            if (t == 0) lds_start[cnt] = e;
        }

        // ---- wave 0: decoupled lookback (64 predecessors per probe) ----
        int prefix = 0;
        if (vt > 0) {
            int look = vt - 1;
            for (;;) {
                int idx = look - t;
                unsigned w = ST_PRE;     // virtual prefix 0 before tile 0
                if (idx >= 0)
                    w = __hip_atomic_load(&ws[WS_TILES + idx], __ATOMIC_ACQUIRE,
                                          __HIP_MEMORY_SCOPE_AGENT);
                unsigned st = w >> ST_SHIFT;
                unsigned long long preB = __ballot(st == 2u);
                unsigned long long invB = __ballot(st == 0u);
                if (preB) {
                    int lp = __ffsll(preB) - 1;   // nearest prefix lane
                    if (!(invB & ((lp > 0) ? ((1ull << lp) - 1ull) : 0ull))) {
                        int contrib = (t <= lp) ? (int)(w & VAL_MASK) : 0;
                        for (int o = 32; o; o >>= 1) contrib += __shfl_down(contrib, o);
                        prefix += __shfl(contrib, 0);
                        break;
                    }
                } else if (!invB) {
                    int contrib = (int)(w & VAL_MASK);
                    for (int o = 32; o; o >>= 1) contrib += __shfl_down(contrib, o);
                    prefix += __shfl(contrib, 0);
                    look -= 64;
                    continue;
                }
                __builtin_amdgcn_s_sleep(1);   // window incomplete: retry
            }
        }
        if (t == 0) {
            lds_bc[1] = prefix;
            unsigned incl = (unsigned)(prefix + cnt);
            __hip_atomic_store(&ws[WS_TILES + vt], ST_PRE | incl,
                               __ATOMIC_RELEASE, __HIP_MEMORY_SCOPE_AGENT);
            if (vt == NTILES - 1)
                __hip_atomic_store(&ws[WS_TOTAL], ST_AGG | incl,
                                   __ATOMIC_RELEASE, __HIP_MEMORY_SCOPE_AGENT);
        }
    }

    // ---- get num_runs (last-ticket block set it; everyone else spins briefly) ----
    if (t == 0) {
        unsigned w;
        do {
            w = __hip_atomic_load(&ws[WS_TOTAL], __ATOMIC_ACQUIRE, __HIP_MEMORY_SCOPE_AGENT);
            if (!(w >> ST_SHIFT)) __builtin_amdgcn_s_sleep(2);
        } while (!(w >> ST_SHIFT));
        lds_bc[2] = (int)(w & VAL_MASK);
    }
    __syncthreads();

    const int prefix    = lds_bc[1];
    const int num_valid = lds_bc[2] - 1;   // final run is never emitted

    // ---- emission: this block's runs -> run_id + full 512B padded row ----
    const int wid = t >> 6, lane = t & 63;
    for (int r = wid; r < cnt; r += NTHR / 64) {
        int rank = prefix + r;
        if (rank >= num_valid) break;      // only the globally-final run hits this
        int s = lds_start[r];
        int e = lds_start[r + 1];          // contiguous runs: end == next start
        int len = e - s; if (len > L_CAP) len = L_CAP;
        if (lane == 0) out[rank] = (float)ids[s];
        float* row = out + M_CAP + (long)rank * L_CAP;
        float f0 = (lane < len)      ? feat[s + lane]      : 0.0f;
        float f1 = (lane + 64 < len) ? feat[s + lane + 64] : 0.0f;
        row[lane]      = f0;
        row[lane + 64] = f1;
    }

    // ---- invalid tail: run_ids = -1, rows = 0 (last-ticket block only) ----
    if (vt == NTILES - 1) {
        for (int i = num_valid + t; i < M_CAP; i += NTHR)
            out[i] = -1.0f;
        long p0 = (long)num_valid * L_CAP;
        long pN = (long)M_CAP * L_CAP;
        for (long p = p0 + t; p < pN; p += NTHR)
            out[M_CAP + p] = 0.0f;
    }
}

// ---------------------------------------------------------------------------
extern "C" void kernel_launch(void* const* d_in, const int* in_sizes, int n_in,
                              void* d_out, int out_size, void* d_ws, size_t ws_size,
                              hipStream_t stream) {
    const int* ids    = (const int*)d_in[0];    // int32
    const float* feat = (const float*)d_in[1];  // float32
    float* out        = (float*)d_out;          // float32
    unsigned int* ws  = (unsigned int*)d_ws;

    // lookback metadata must start zeroed (ws is re-poisoned 0xAA each launch)
    hipMemsetAsync(ws, 0, WS_WORDS * sizeof(unsigned int), stream);

    k_scan_emit<<<NTILES, NTHR, 0, stream>>>(ids, feat, out, ws);
}

// Round 5
// 216.720 us; speedup vs baseline: 2.2590x; 1.4939x over previous
//
#include <hip/hip_runtime.h>

// Problem constants (fixed by the reference file)
#define N_ELEM   4194304
#define NUM_IDS  262144
#define M_CAP    (NUM_IDS + 1)       // 262145
#define L_CAP    128

#define NTILES   1024
#define TILE     4096                // NTILES * TILE == N_ELEM
#define NTHR     256
#define EPT      16                  // TILE / NTHR, contiguous per thread

// ws layout (uint words):
//  [0]                ticket counter
//  [1]                num_runs (set by last tile)
//  [4 .. 4+NTILES)    tile words: 0=invalid, AGG|cnt, PRE|incl_prefix
//  [4096 ..)          run_start[M_CAP]
//  [266244 ..)        run_vid[M_CAP]   (offset % 4 == 0 -> int4-aligned)
#define WS_TICKET 0
#define WS_TOTAL  1
#define WS_TILES  4
#define META_WORDS (WS_TILES + NTILES)
#define RS_OFF    4096
#define RV_OFF    (RS_OFF + M_CAP + 3)   // 266244

#define ST_SHIFT  30
#define ST_AGG    (1u << ST_SHIFT)
#define ST_PRE    (2u << ST_SHIFT)
#define VAL_MASK  ((1u << ST_SHIFT) - 1u)

// Writer geometry: flat float4 units over the whole out buffer
#define P_TOTAL   (M_CAP * L_CAP)        // 33554560
#define OUT_TOTAL (M_CAP + P_TOTAL)      // 33816705
#define R1_F4     (NUM_IDS / 4)          // 65536 f4 covering out[0..262144)
#define Q0        (M_CAP + 3)            // 262148: first 16B-aligned padded elem
#define NF4       ((OUT_TOTAL - Q0) / 4) // 8388639 (1 leftover float at end)
#define WBLK      2048
#define WTHR      256
#define WTOT      (WBLK * WTHR)

// ---------------------------------------------------------------------------
// Kernel 1: run detection + decoupled-lookback scan of run counts, then
// scatter run_start[rank], run_vid[rank]. Packed state|value words make
// RELAXED agent-scope atomics sufficient (no acquire invalidate storms).
// No global total-spin: the writer kernel is stream-ordered behind us.
// ---------------------------------------------------------------------------
__global__ void __launch_bounds__(NTHR)
k_scan(const int* __restrict__ ids, unsigned int* __restrict__ ws) {
    __shared__ int sm[NTHR];
    __shared__ int bc[2];   // 0: vtile, 1: prefix

    const int t = threadIdx.x;

    if (t == 0) bc[0] = (int)atomicAdd(&ws[WS_TICKET], 1u);
    __syncthreads();
    const int vt = bc[0];
    const int base = vt * TILE + t * EPT;

    // ---- run-start flags for 16 contiguous ids ----
    int v[EPT];
    {
        const int4* p4 = (const int4*)(ids + base);
        int4 a = p4[0], b4 = p4[1], c4 = p4[2], d4 = p4[3];
        v[0]=a.x; v[1]=a.y; v[2]=a.z; v[3]=a.w;
        v[4]=b4.x; v[5]=b4.y; v[6]=b4.z; v[7]=b4.w;
        v[8]=c4.x; v[9]=c4.y; v[10]=c4.z; v[11]=c4.w;
        v[12]=d4.x; v[13]=d4.y; v[14]=d4.z; v[15]=d4.w;
    }
    const int prev = (base == 0) ? -1 : ids[base - 1];  // ids >= 0 -> sentinel

    unsigned flagbits = 0;
    int c = 0;
#pragma unroll
    for (int j = 0; j < EPT; ++j) {
        int f = (v[j] != ((j == 0) ? prev : v[j - 1]));
        flagbits |= ((unsigned)f << j);
        c += f;
    }

    // ---- block scan of per-thread counts ----
    sm[t] = c;
    __syncthreads();
    for (int off = 1; off < NTHR; off <<= 1) {
        int val = (t >= off) ? sm[t - off] : 0;
        __syncthreads();
        if (t >= off) sm[t] += val;
        __syncthreads();
    }
    const int excl = sm[t] - c;
    const int cnt  = sm[NTHR - 1];

    // ---- publish aggregate ASAP (relaxed: packed word is self-ordering) ----
    if (t == 0) {
        unsigned w = (vt == 0) ? (ST_PRE | (unsigned)cnt) : (ST_AGG | (unsigned)cnt);
        __hip_atomic_store(&ws[WS_TILES + vt], w, __ATOMIC_RELAXED,
                           __HIP_MEMORY_SCOPE_AGENT);
    }

    // ---- wave 0: decoupled lookback (64 predecessors per probe) ----
    if (t < 64) {
        int prefix = 0;
        if (vt > 0) {
            int look = vt - 1;
            for (;;) {
                int idx = look - t;
                unsigned w = ST_PRE;   // virtual prefix 0 before tile 0
                if (idx >= 0)
                    w = __hip_atomic_load(&ws[WS_TILES + idx], __ATOMIC_RELAXED,
                                          __HIP_MEMORY_SCOPE_AGENT);
                unsigned st = w >> ST_SHIFT;
                unsigned long long preB = __ballot(st == 2u);
                unsigned long long invB = __ballot(st == 0u);
                if (preB) {
                    int lp = __ffsll(preB) - 1;   // nearest prefix lane
                    if (!(invB & ((lp > 0) ? ((1ull << lp) - 1ull) : 0ull))) {
                        int contrib = (t <= lp) ? (int)(w & VAL_MASK) : 0;
                        for (int o = 32; o; o >>= 1) contrib += __shfl_down(contrib, o);
                        prefix += __shfl(contrib, 0);
                        break;
                    }
                } else if (!invB) {
                    int contrib = (int)(w & VAL_MASK);
                    for (int o = 32; o; o >>= 1) contrib += __shfl_down(contrib, o);
                    prefix += __shfl(contrib, 0);
                    look -= 64;
                    continue;
                }
                __builtin_amdgcn_s_sleep(1);
            }
        }
        if (t == 0) {
            bc[1] = prefix;
            unsigned incl = (unsigned)(prefix + cnt);
            __hip_atomic_store(&ws[WS_TILES + vt], ST_PRE | incl,
                               __ATOMIC_RELAXED, __HIP_MEMORY_SCOPE_AGENT);
            if (vt == NTILES - 1)
                __hip_atomic_store(&ws[WS_TOTAL], incl, __ATOMIC_RELAXED,
                                   __HIP_MEMORY_SCOPE_AGENT);
        }
    }
    __syncthreads();

    // ---- scatter run_start / run_vid at global rank ----
    {
        int* run_start = (int*)(ws + RS_OFF);
        int* run_vid   = (int*)(ws + RV_OFF);
        int rank = bc[1] + excl;
#pragma unroll
        for (int j = 0; j < EPT; ++j) {
            if (flagbits & (1u << j)) {
                run_start[rank] = base + j;
                run_vid[rank]   = v[j];
                ++rank;
            }
        }
    }
}

// ---------------------------------------------------------------------------
// Kernel 2: flat float4 writer over the whole output.
//   units u < R1_F4           : run_ids region, value from run_vid / -1
//   units u >= R1_F4          : padded region at element p = 3 + 4*(u-R1_F4)
// Runs contiguous: len[m] = run_start[m+1] - run_start[m] (capped at 128).
// ---------------------------------------------------------------------------
__global__ void __launch_bounds__(WTHR)
k_write(const unsigned int* __restrict__ ws,
        const float* __restrict__ feat,
        float* __restrict__ out) {
    const int* run_start = (const int*)(ws + RS_OFF);
    const int* run_vid   = (const int*)(ws + RV_OFF);
    const int num_valid  = (int)(ws[WS_TOTAL] & VAL_MASK) - 1;

    const int gtid = blockIdx.x * WTHR + threadIdx.x;

    if (gtid == 0) {
        out[M_CAP - 1] = -1.0f;                    // last run_id slot
        int s0 = 0, L0 = 0;
        if (num_valid > 0) {
            s0 = run_start[0];
            L0 = run_start[1] - s0; if (L0 > L_CAP) L0 = L_CAP;
        }
#pragma unroll
        for (int p = 0; p < 3; ++p)                // padded elems before Q0
            out[M_CAP + p] = (p < L0) ? feat[s0 + p] : 0.0f;
        out[OUT_TOTAL - 1] = 0.0f;                 // leftover last elem (invalid row)
    }

    const int total_u = R1_F4 + NF4;
    for (int u = gtid; u < total_u; u += WTOT) {
        if (u < R1_F4) {
            int4 rv = ((const int4*)run_vid)[u];   // poison beyond num_runs: masked
            int m = 4 * u;
            float4 r;
            r.x = (m     < num_valid) ? (float)rv.x : -1.0f;
            r.y = (m + 1 < num_valid) ? (float)rv.y : -1.0f;
            r.z = (m + 2 < num_valid) ? (float)rv.z : -1.0f;
            r.w = (m + 3 < num_valid) ? (float)rv.w : -1.0f;
            ((float4*)out)[u] = r;
        } else {
            int k = u - R1_F4;
            int p = 3 + 4 * k;                     // padded-region element index
            int m0 = p >> 7, c0 = p & 127;         // c0 in {3,7,...,127}
            int s0 = 0, L0 = 0;
            if (m0 < num_valid) {
                s0 = run_start[m0];
                L0 = run_start[m0 + 1] - s0; if (L0 > L_CAP) L0 = L_CAP;
            }
            float4 r;
            if (c0 != 127) {                       // whole f4 inside row m0
                r.x = (c0     < L0) ? feat[s0 + c0]     : 0.0f;
                r.y = (c0 + 1 < L0) ? feat[s0 + c0 + 1] : 0.0f;
                r.z = (c0 + 2 < L0) ? feat[s0 + c0 + 2] : 0.0f;
                r.w = (c0 + 3 < L0) ? feat[s0 + c0 + 3] : 0.0f;
            } else {                               // x ends row m0; y,z,w open row m0+1
                int m1 = m0 + 1, s1 = 0, L1 = 0;
                if (m1 < num_valid) {
                    s1 = run_start[m1];
                    L1 = run_start[m1 + 1] - s1; if (L1 > L_CAP) L1 = L_CAP;
                }
                r.x = (L0 == L_CAP) ? feat[s0 + 127] : 0.0f;
                r.y = (0 < L1) ? feat[s1]     : 0.0f;
                r.z = (1 < L1) ? feat[s1 + 1] : 0.0f;
                r.w = (2 < L1) ? feat[s1 + 2] : 0.0f;
            }
            *(float4*)(out + Q0 + 4 * (size_t)k) = r;
        }
    }
}

// ---------------------------------------------------------------------------
extern "C" void kernel_launch(void* const* d_in, const int* in_sizes, int n_in,
                              void* d_out, int out_size, void* d_ws, size_t ws_size,
                              hipStream_t stream) {
    const int* ids    = (const int*)d_in[0];    // int32
    const float* feat = (const float*)d_in[1];  // float32
    float* out        = (float*)d_out;          // float32
    unsigned int* ws  = (unsigned int*)d_ws;

    // lookback metadata must start zeroed (ws is re-poisoned 0xAA each launch)
    hipMemsetAsync(ws, 0, META_WORDS * sizeof(unsigned int), stream);

    k_scan<<<NTILES, NTHR, 0, stream>>>(ids, ws);
    k_write<<<WBLK, WTHR, 0, stream>>>(ws, feat, out);
}

// Round 6
// 197.512 us; speedup vs baseline: 2.4787x; 1.0972x over previous
//
#include <hip/hip_runtime.h>

// Problem constants (fixed by the reference file)
#define N_ELEM   4194304
#define NUM_IDS  262144
#define M_CAP    (NUM_IDS + 1)       // 262145
#define L_CAP    128

#define NTILES   1024
#define TILE     4096                // NTILES * TILE == N_ELEM
#define NTHR     256
#define EPT      16                  // TILE / NTHR, contiguous per thread

// ws layout (uint words):
//  [0]                ticket counter
//  [1]                num_runs (set by last tile)
//  [4 .. 4+NTILES)    tile words: 0=invalid, AGG|cnt, PRE|incl_prefix
//  [4096 ..)          run_start[M_CAP (+3 pad)]
//  [266244 ..)        run_vid_f[M_CAP]  (float; offset % 4 == 0 -> float4-aligned)
#define WS_TICKET 0
#define WS_TOTAL  1
#define WS_TILES  4
#define META_WORDS (WS_TILES + NTILES)
#define RS_OFF    4096
#define RV_OFF    (RS_OFF + M_CAP + 3)   // 266244

#define ST_SHIFT  30
#define ST_AGG    (1u << ST_SHIFT)
#define ST_PRE    (2u << ST_SHIFT)
#define VAL_MASK  ((1u << ST_SHIFT) - 1u)

// Writer geometry
#define P_TOTAL   (M_CAP * L_CAP)        // 33554560 padded elements
#define OUT_TOTAL (M_CAP + P_TOTAL)      // 33816705 floats
#define PAD_BLK   2048                   // blocks over rows 0..262143, 128 rows each
#define RID_BLK   16                     // blocks over run_ids region (65536 f4)
#define WTHR      256

// ---------------------------------------------------------------------------
// Kernel 1: run detection + decoupled-lookback scan of run counts, then
// scatter run_start[rank] (int) and run_vid_f[rank] (float). Packed
// state|value words -> RELAXED agent-scope atomics suffice. All 1024 blocks
// are co-resident (4 blocks/CU), so lookback cannot deadlock.
// ---------------------------------------------------------------------------
__global__ void __launch_bounds__(NTHR)
k_scan(const int* __restrict__ ids, unsigned int* __restrict__ ws) {
    __shared__ int sm[NTHR];
    __shared__ int bc[2];   // 0: vtile, 1: prefix

    const int t = threadIdx.x;

    if (t == 0) bc[0] = (int)atomicAdd(&ws[WS_TICKET], 1u);
    __syncthreads();
    const int vt = bc[0];
    const int base = vt * TILE + t * EPT;

    // ---- run-start flags for 16 contiguous ids ----
    int v[EPT];
    {
        const int4* p4 = (const int4*)(ids + base);
        int4 a = p4[0], b4 = p4[1], c4 = p4[2], d4 = p4[3];
        v[0]=a.x; v[1]=a.y; v[2]=a.z; v[3]=a.w;
        v[4]=b4.x; v[5]=b4.y; v[6]=b4.z; v[7]=b4.w;
        v[8]=c4.x; v[9]=c4.y; v[10]=c4.z; v[11]=c4.w;
        v[12]=d4.x; v[13]=d4.y; v[14]=d4.z; v[15]=d4.w;
    }
    const int prev = (base == 0) ? -1 : ids[base - 1];  // ids >= 0 -> sentinel

    unsigned flagbits = 0;
    int c = 0;
#pragma unroll
    for (int j = 0; j < EPT; ++j) {
        int f = (v[j] != ((j == 0) ? prev : v[j - 1]));
        flagbits |= ((unsigned)f << j);
        c += f;
    }

    // ---- block scan of per-thread counts ----
    sm[t] = c;
    __syncthreads();
    for (int off = 1; off < NTHR; off <<= 1) {
        int val = (t >= off) ? sm[t - off] : 0;
        __syncthreads();
        if (t >= off) sm[t] += val;
        __syncthreads();
    }
    const int excl = sm[t] - c;
    const int cnt  = sm[NTHR - 1];

    // ---- publish aggregate ASAP ----
    if (t == 0) {
        unsigned w = (vt == 0) ? (ST_PRE | (unsigned)cnt) : (ST_AGG | (unsigned)cnt);
        __hip_atomic_store(&ws[WS_TILES + vt], w, __ATOMIC_RELAXED,
                           __HIP_MEMORY_SCOPE_AGENT);
    }

    // ---- wave 0: decoupled lookback (64 predecessors per probe) ----
    if (t < 64) {
        int prefix = 0;
        if (vt > 0) {
            int look = vt - 1;
            for (;;) {
                int idx = look - t;
                unsigned w = ST_PRE;   // virtual prefix 0 before tile 0
                if (idx >= 0)
                    w = __hip_atomic_load(&ws[WS_TILES + idx], __ATOMIC_RELAXED,
                                          __HIP_MEMORY_SCOPE_AGENT);
                unsigned st = w >> ST_SHIFT;
                unsigned long long preB = __ballot(st == 2u);
                unsigned long long invB = __ballot(st == 0u);
                if (preB) {
                    int lp = __ffsll(preB) - 1;   // nearest prefix lane
                    if (!(invB & ((lp > 0) ? ((1ull << lp) - 1ull) : 0ull))) {
                        int contrib = (t <= lp) ? (int)(w & VAL_MASK) : 0;
                        for (int o = 32; o; o >>= 1) contrib += __shfl_down(contrib, o);
                        prefix += __shfl(contrib, 0);
                        break;
                    }
                } else if (!invB) {
                    int contrib = (int)(w & VAL_MASK);
                    for (int o = 32; o; o >>= 1) contrib += __shfl_down(contrib, o);
                    prefix += __shfl(contrib, 0);
                    look -= 64;
                    continue;
                }
                __builtin_amdgcn_s_sleep(1);
            }
        }
        if (t == 0) {
            bc[1] = prefix;
            unsigned incl = (unsigned)(prefix + cnt);
            __hip_atomic_store(&ws[WS_TILES + vt], ST_PRE | incl,
                               __ATOMIC_RELAXED, __HIP_MEMORY_SCOPE_AGENT);
            if (vt == NTILES - 1)
                __hip_atomic_store(&ws[WS_TOTAL], incl, __ATOMIC_RELAXED,
                                   __HIP_MEMORY_SCOPE_AGENT);
        }
    }
    __syncthreads();

    // ---- scatter run_start / run_vid (as float) at global rank ----
    {
        int*   run_start = (int*)(ws + RS_OFF);
        float* run_vid_f = (float*)(ws + RV_OFF);
        int rank = bc[1] + excl;
#pragma unroll
        for (int j = 0; j < EPT; ++j) {
            if (flagbits & (1u << j)) {
                run_start[rank] = base + j;
                run_vid_f[rank] = (float)v[j];
                ++rank;
            }
        }
    }
}

// ---------------------------------------------------------------------------
// Kernel 2: block-contiguous writer.
//   blocks [0, PAD_BLK):      128 padded rows each; run_start slice staged in
//                             LDS (130 ints); 4096 aligned float4 units/block
//                             covering p_local in [3, 16387).
//   blocks [PAD_BLK, +RID_BLK): run_ids region, 4096 f4 units each (copy of
//                             run_vid_f with validity select).
//   block  PAD_BLK+RID_BLK:   edges (p=0..2, out[262144], row 262144 zeros).
// Runs contiguous: len[m] = run_start[m+1] - run_start[m] (capped at 128).
// ---------------------------------------------------------------------------
__global__ void __launch_bounds__(WTHR)
k_write(const unsigned int* __restrict__ ws,
        const float* __restrict__ feat,
        float* __restrict__ out) {
    const int*   run_start = (const int*)(ws + RS_OFF);
    const float* run_vid_f = (const float*)(ws + RV_OFF);
    const int num_valid    = (int)(ws[WS_TOTAL] & VAL_MASK) - 1;

    const int b = blockIdx.x;
    const int t = threadIdx.x;

    if (b < PAD_BLK) {
        __shared__ int sm[130];
        const int rb = b * 128;                 // first row of this block
        // stage run_start[rb .. rb+129] (max index 262145 < region size 262148)
        if (t < 130) sm[t] = run_start[rb + t];
        __syncthreads();

        float* obase = out + M_CAP + (size_t)rb * L_CAP;   // p_local = 0 here
#pragma unroll 4
        for (int i = 0; i < 16; ++i) {
            const int j  = t + i * WTHR;        // unit index in [0, 4096)
            const int pl = 3 + 4 * j;           // p_local in [3, 16387)
            const int m  = pl >> 7;             // local row 0..127 (128 on last unit)
            const int c0 = pl & 127;            // in {3, 7, ..., 127}

            int s0 = sm[m];
            int L0 = sm[m + 1] - s0; if (L0 > L_CAP) L0 = L_CAP;
            if (rb + m >= num_valid) L0 = 0;

            float4 r;
            if (c0 != 127) {                    // unit wholly inside row m
                r.x = (c0     < L0) ? feat[s0 + c0]     : 0.0f;
                r.y = (c0 + 1 < L0) ? feat[s0 + c0 + 1] : 0.0f;
                r.z = (c0 + 2 < L0) ? feat[s0 + c0 + 2] : 0.0f;
                r.w = (c0 + 3 < L0) ? feat[s0 + c0 + 3] : 0.0f;
            } else {                            // x ends row m; y,z,w open row m+1
                int s1 = sm[m + 1];
                int L1 = sm[m + 2] - s1; if (L1 > L_CAP) L1 = L_CAP;
                if (rb + m + 1 >= num_valid) L1 = 0;
                r.x = (L0 == L_CAP) ? feat[s0 + 127] : 0.0f;
                r.y = (0 < L1) ? feat[s1]     : 0.0f;
                r.z = (1 < L1) ? feat[s1 + 1] : 0.0f;
                r.w = (2 < L1) ? feat[s1 + 2] : 0.0f;
            }
            *(float4*)(obase + pl) = r;         // out idx = M_CAP + rb*128 + pl ≡ 0 mod 4
        }
    } else if (b < PAD_BLK + RID_BLK) {
        const int ub = (b - PAD_BLK) * 4096;    // f4 units over out[0..262144)
#pragma unroll 4
        for (int i = 0; i < 16; ++i) {
            const int u = ub + t + i * WTHR;
            float4 rv = ((const float4*)run_vid_f)[u];  // poison masked by select
            const int m = 4 * u;
            float4 r;
            r.x = (m     < num_valid) ? rv.x : -1.0f;
            r.y = (m + 1 < num_valid) ? rv.y : -1.0f;
            r.z = (m + 2 < num_valid) ? rv.z : -1.0f;
            r.w = (m + 3 < num_valid) ? rv.w : -1.0f;
            ((float4*)out)[u] = r;
        }
    } else {
        // ---- edge block ----
        if (t == 0) {
            out[M_CAP - 1] = -1.0f;             // run_id slot m = 262144
            int s0 = 0, L0 = 0;
            if (num_valid > 0) {
                s0 = run_start[0];
                L0 = run_start[1] - s0; if (L0 > L_CAP) L0 = L_CAP;
            }
#pragma unroll
            for (int p = 0; p < 3; ++p)         // padded p = 0..2 (row 0 head)
                out[M_CAP + p] = (p < L0) ? feat[s0 + p] : 0.0f;
        }
        // row 262144 (always invalid): cols 3..127 -> zeros
        const size_t base = (size_t)M_CAP + (size_t)262144 * L_CAP;
        if (t < 31) {
            float4 z = {0.0f, 0.0f, 0.0f, 0.0f};
            *(float4*)(out + base + 3 + 4 * t) = z;
        }
        if (t == 31) out[base + 127] = 0.0f;    // final element
    }
}

// ---------------------------------------------------------------------------
extern "C" void kernel_launch(void* const* d_in, const int* in_sizes, int n_in,
                              void* d_out, int out_size, void* d_ws, size_t ws_size,
                              hipStream_t stream) {
    const int* ids    = (const int*)d_in[0];    // int32
    const float* feat = (const float*)d_in[1];  // float32
    float* out        = (float*)d_out;          // float32
    unsigned int* ws  = (unsigned int*)d_ws;

    // lookback metadata must start zeroed (ws is re-poisoned 0xAA each launch)
    hipMemsetAsync(ws, 0, META_WORDS * sizeof(unsigned int), stream);

    k_scan<<<NTILES, NTHR, 0, stream>>>(ids, ws);
    k_write<<<PAD_BLK + RID_BLK + 1, WTHR, 0, stream>>>(ws, feat, out);
}